// Round 1
// baseline (135.478 us; speedup 1.0000x reference)
//
#include <hip/hip_runtime.h>

// 8-tap reconstruction filters (sym4-style), float32.
#define LO0 0.23037781330885523f
#define LO1 0.7148465705525415f
#define LO2 0.6308807679295904f
#define LO3 -0.02798376941698385f
#define LO4 -0.18703481171888114f
#define LO5 0.030841381835986965f
#define LO6 0.032883011666982945f
#define LO7 -0.010597401784997278f

#define HI0 -0.010597401784997278f
#define HI1 -0.032883011666982945f
#define HI2 0.030841381835986965f
#define HI3 0.18703481171888114f
#define HI4 -0.02798376941698385f
#define HI5 -0.6308807679295904f
#define HI6 0.7148465705525415f
#define HI7 -0.23037781330885523f

// One IDWT synthesis level.
// out[k], k in [0, 2n-7]:
//   k=2m:   sum_t x[m+t]*LO[6-2t] + d[m+t]*HI[6-2t]
//   k=2m+1: sum_t x[m+t]*LO[7-2t] + d[m+t]*HI[7-2t]
// m in [0, n-4]; all x/d indices m..m+3 are in-bounds (no boundary cases).
__global__ __launch_bounds__(256) void idwt_level_kernel(
    const float* __restrict__ x, const float* __restrict__ d,
    float* __restrict__ out,
    int n, long long xs, long long ds, long long os) {
    int m = blockIdx.x * blockDim.x + threadIdx.x;
    int mtot = n - 3;
    if (m >= mtot) return;
    int row = blockIdx.y;

    const float* xr = x + (long long)row * xs + m;
    const float* dr = d + (long long)row * ds + m;

    float a0 = xr[0], a1 = xr[1], a2 = xr[2], a3 = xr[3];
    float b0 = dr[0], b1 = dr[1], b2 = dr[2], b3 = dr[3];

    float e = a0 * LO6 + b0 * HI6;
    e = fmaf(a1, LO4, e); e = fmaf(b1, HI4, e);
    e = fmaf(a2, LO2, e); e = fmaf(b2, HI2, e);
    e = fmaf(a3, LO0, e); e = fmaf(b3, HI0, e);

    float o = a0 * LO7 + b0 * HI7;
    o = fmaf(a1, LO5, o); o = fmaf(b1, HI5, o);
    o = fmaf(a2, LO3, o); o = fmaf(b2, HI3, o);
    o = fmaf(a3, LO1, o); o = fmaf(b3, HI1, o);

    float2 r = make_float2(e, o);
    *reinterpret_cast<float2*>(out + (long long)row * os + 2 * m) = r;
}

static inline void run_level(const float* x, const float* d, float* out,
                             int n, long long xs, long long ds, long long os,
                             hipStream_t stream) {
    int mtot = n - 3;
    dim3 block(256);
    dim3 grid((mtot + 255) / 256, 128);
    idwt_level_kernel<<<grid, block, 0, stream>>>(x, d, out, n, xs, ds, os);
}

extern "C" void kernel_launch(void* const* d_in, const int* in_sizes, int n_in,
                              void* d_out, int out_size, void* d_ws, size_t ws_size,
                              hipStream_t stream) {
    const float* a  = (const float*)d_in[0];  // (128, 4102)
    const float* d6 = (const float*)d_in[1];  // (128, 4102)
    const float* d5 = (const float*)d_in[2];  // (128, 8198)
    const float* d4 = (const float*)d_in[3];  // (128, 16390)
    const float* d3 = (const float*)d_in[4];  // (128, 32774)
    const float* d2 = (const float*)d_in[5];  // (128, 65541)
    const float* d1 = (const float*)d_in[6];  // (128, 131075)

    float* OUT = (float*)d_out;          // final (128, 262144); also scratch B
    float* A   = (float*)d_ws;           // scratch A: needs 131076*128*4 = 67.1 MB

    // L1: (a, d6) 4102 -> 8198  [A]
    run_level(a,   d6, A,   4102,  4102,  4102,  8198,  stream);
    // L2: (A, d5) 8198 -> 16390 [OUT-as-scratch]
    run_level(A,   d5, OUT, 8198,  8198,  8198,  16390, stream);
    // L3: (OUT, d4) 16390 -> 32774 [A]
    run_level(OUT, d4, A,   16390, 16390, 16390, 32774, stream);
    // L4: (A, d3) 32774 -> 65542 [OUT-as-scratch]
    run_level(A,   d3, OUT, 32774, 32774, 32774, 65542, stream);
    // L5: (OUT trimmed to 65541, d2) -> 131076 [A]
    run_level(OUT, d2, A,   65541, 65542, 65541, 131076, stream);
    // L6: (A trimmed to 131075, d1) -> 262144 [final OUT]
    run_level(A,   d1, OUT, 131075, 131076, 131075, 262144, stream);
}

// Round 2
// 90.222 us; speedup vs baseline: 1.5016x; 1.5016x over previous
//
#include <hip/hip_runtime.h>

// 8-tap reconstruction filters (sym4-style), float32.
#define LO0 0.23037781330885523f
#define LO1 0.7148465705525415f
#define LO2 0.6308807679295904f
#define LO3 -0.02798376941698385f
#define LO4 -0.18703481171888114f
#define LO5 0.030841381835986965f
#define LO6 0.032883011666982945f
#define LO7 -0.010597401784997278f

#define HI0 -0.010597401784997278f
#define HI1 -0.032883011666982945f
#define HI2 0.030841381835986965f
#define HI3 0.18703481171888114f
#define HI4 -0.02798376941698385f
#define HI5 -0.6308807679295904f
#define HI6 0.7148465705525415f
#define HI7 -0.23037781330885523f

#define T_OUT 8192      // final-output columns per workgroup tile
#define NTHREADS 256
#define BUF_SZ 4104     // floats per LDS buffer (max needed: 4100)

// Synthesis pair: given x[m..m+3], d[m..m+3] produce out[2m] (e), out[2m+1] (o).
__device__ __forceinline__ void synth_pair(
    float x0, float x1, float x2, float x3,
    float g0, float g1, float g2, float g3,
    float& e, float& o)
{
    e = x0 * LO6 + g0 * HI6;
    e = fmaf(x1, LO4, e); e = fmaf(g1, HI4, e);
    e = fmaf(x2, LO2, e); e = fmaf(g2, HI2, e);
    e = fmaf(x3, LO0, e); e = fmaf(g3, HI0, e);
    o = x0 * LO7 + g0 * HI7;
    o = fmaf(x1, LO5, o); o = fmaf(g1, HI5, o);
    o = fmaf(x2, LO3, o); o = fmaf(g2, HI3, o);
    o = fmaf(x3, LO1, o); o = fmaf(g3, HI1, o);
}

// Fully fused 6-level IDWT. One block = one (row, T_OUT-column) tile of the
// final output. All intermediates live in LDS ping-pong buffers.
// Level l (1..6): out[k] uses x[k>>1 .. k>>1+3] and d_l[same]; pair index
// m produces out[2m], out[2m+1]. Needed ranges per tile (derived top-down):
//   mlo[l] = lo>>1, mhi[l] = (hi-1)>>1, then input range [mlo, mhi+4).
// Max indices are exactly len-1 at every level (verified) -> no clamping.
__global__ __launch_bounds__(NTHREADS) void idwt_fused_kernel(
    const float* __restrict__ a,
    const float* __restrict__ d6, const float* __restrict__ d5,
    const float* __restrict__ d4, const float* __restrict__ d3,
    const float* __restrict__ d2, const float* __restrict__ d1,
    float* __restrict__ out)
{
    __shared__ float bufA[BUF_SZ], bufB[BUF_SZ], bufD[BUF_SZ];

    const int row = blockIdx.y;
    const int K0  = blockIdx.x * T_OUT;
    const int tid = threadIdx.x;

    // Per-level pair ranges (all compile-time-unrolled -> registers).
    int mlo[7], mhi[7];
    {
        int lo = K0, hi = K0 + T_OUT;
#pragma unroll
        for (int l = 6; l >= 1; --l) {
            mlo[l] = lo >> 1;
            mhi[l] = (hi - 1) >> 1;
            lo = mlo[l];
            hi = mhi[l] + 4;
        }
    }

    // Stage a-tile: global indices [mlo[1], mhi[1]+3] -> bufA[0..]
    {
        const float* ar = a + (long long)row * 4102;
        const int lo = mlo[1], n = mhi[1] + 4 - lo;
        for (int i = tid; i < n; i += NTHREADS) bufA[i] = ar[lo + i];
    }

    const float* XB  = bufA;  // current level's x tile
    float*       OB  = bufB;  // current level's output tile
    int xbase = mlo[1];       // absolute index of XB[0]

    const float* dp[7];
    long long    ds[7];
    dp[1] = d6; ds[1] = 4102;
    dp[2] = d5; ds[2] = 8198;
    dp[3] = d4; ds[3] = 16390;
    dp[4] = d3; ds[4] = 32774;
    dp[5] = d2; ds[5] = 65541;
    dp[6] = d1; ds[6] = 131075;

#pragma unroll
    for (int l = 1; l <= 6; ++l) {
        // Stage d_l tile: global indices [mlo[l], mhi[l]+3] -> bufD[0..]
        {
            const float* dr = dp[l] + (long long)row * ds[l];
            const int lo = mlo[l], n = mhi[l] + 4 - lo;
            for (int i = tid; i < n; i += NTHREADS) bufD[i] = dr[lo + i];
        }
        __syncthreads();

        const int npairs = mhi[l] - mlo[l] + 1;
        if (l < 6) {
            for (int p = tid; p < npairs; p += NTHREADS) {
                const int base = mlo[l] + p - xbase;
                float e, o;
                synth_pair(XB[base], XB[base+1], XB[base+2], XB[base+3],
                           bufD[p], bufD[p+1], bufD[p+2], bufD[p+3], e, o);
                OB[2*p]   = e;
                OB[2*p+1] = o;
            }
            __syncthreads();
            // Output becomes next level's x; base = absolute index 2*mlo[l].
            const float* t = XB; XB = OB; OB = (float*)t;
            xbase = 2 * mlo[l];
        } else {
            // Final level: write straight to global, float2 per pair.
            float2* orow = reinterpret_cast<float2*>(
                out + (long long)row * 262144 + 2LL * mlo[6]);
            for (int p = tid; p < npairs; p += NTHREADS) {
                const int base = mlo[l] + p - xbase;
                float e, o;
                synth_pair(XB[base], XB[base+1], XB[base+2], XB[base+3],
                           bufD[p], bufD[p+1], bufD[p+2], bufD[p+3], e, o);
                orow[p] = make_float2(e, o);
            }
        }
    }
}

extern "C" void kernel_launch(void* const* d_in, const int* in_sizes, int n_in,
                              void* d_out, int out_size, void* d_ws, size_t ws_size,
                              hipStream_t stream) {
    const float* a  = (const float*)d_in[0];  // (128, 4102)
    const float* d6 = (const float*)d_in[1];  // (128, 4102)
    const float* d5 = (const float*)d_in[2];  // (128, 8198)
    const float* d4 = (const float*)d_in[3];  // (128, 16390)
    const float* d3 = (const float*)d_in[4];  // (128, 32774)
    const float* d2 = (const float*)d_in[5];  // (128, 65541)
    const float* d1 = (const float*)d_in[6];  // (128, 131075)

    float* OUT = (float*)d_out;               // (128, 262144)

    dim3 block(NTHREADS);
    dim3 grid(262144 / T_OUT, 128);           // 32 x 128 = 4096 blocks
    idwt_fused_kernel<<<grid, block, 0, stream>>>(a, d6, d5, d4, d3, d2, d1, OUT);
}

// Round 3
// 83.006 us; speedup vs baseline: 1.6321x; 1.0869x over previous
//
#include <hip/hip_runtime.h>

// 8-tap reconstruction filters (sym4-style), float32.
#define LO0 0.23037781330885523f
#define LO1 0.7148465705525415f
#define LO2 0.6308807679295904f
#define LO3 -0.02798376941698385f
#define LO4 -0.18703481171888114f
#define LO5 0.030841381835986965f
#define LO6 0.032883011666982945f
#define LO7 -0.010597401784997278f

#define HI0 -0.010597401784997278f
#define HI1 -0.032883011666982945f
#define HI2 0.030841381835986965f
#define HI3 0.18703481171888114f
#define HI4 -0.02798376941698385f
#define HI5 -0.6308807679295904f
#define HI6 0.7148465705525415f
#define HI7 -0.23037781330885523f

#define T_OUT 4096
#define NT 256

// Pair counts per level for T_OUT=4096 (identical for every block because
// K0 is a multiple of 4096 -> mlo[l] = K0>>(7-l) exact, X base offset = 0).
// NP: L1=67 L2=131 L3=259 L4=515 L5=1026 L6=2048. Stage counts = NP+3.
// Edge block verified: max read index == len-1 at every level, no clamping.

__device__ __forceinline__ void synth_pair(
    float x0, float x1, float x2, float x3,
    float g0, float g1, float g2, float g3,
    float& e, float& o)
{
    e = x0 * LO6 + g0 * HI6;
    e = fmaf(x1, LO4, e); e = fmaf(g1, HI4, e);
    e = fmaf(x2, LO2, e); e = fmaf(g2, HI2, e);
    e = fmaf(x3, LO0, e); e = fmaf(g3, HI0, e);
    o = x0 * LO7 + g0 * HI7;
    o = fmaf(x1, LO5, o); o = fmaf(g1, HI5, o);
    o = fmaf(x2, LO3, o); o = fmaf(g2, HI3, o);
    o = fmaf(x3, LO1, o); o = fmaf(g3, HI1, o);
}

// One synthesis level: out[2p],out[2p+1] from X[p..p+3], D[p..p+3].
// Vector path: 4 pairs/thread via aligned float4 LDS reads/writes.
template<int NP, bool FINAL>
__device__ __forceinline__ void level_compute(
    const float* __restrict__ XB, const float* __restrict__ D,
    float* __restrict__ OB, int tid)
{
    constexpr int NVEC = NP & ~3;
    for (int p0 = 4 * tid; p0 < NVEC; p0 += 4 * NT) {
        float4 x0 = *reinterpret_cast<const float4*>(XB + p0);
        float4 x1 = *reinterpret_cast<const float4*>(XB + p0 + 4);
        float4 g0 = *reinterpret_cast<const float4*>(D + p0);
        float4 g1 = *reinterpret_cast<const float4*>(D + p0 + 4);
        float e0,o0,e1,o1,e2,o2,e3,o3;
        synth_pair(x0.x,x0.y,x0.z,x0.w, g0.x,g0.y,g0.z,g0.w, e0,o0);
        synth_pair(x0.y,x0.z,x0.w,x1.x, g0.y,g0.z,g0.w,g1.x, e1,o1);
        synth_pair(x0.z,x0.w,x1.x,x1.y, g0.z,g0.w,g1.x,g1.y, e2,o2);
        synth_pair(x0.w,x1.x,x1.y,x1.z, g0.w,g1.x,g1.y,g1.z, e3,o3);
        *reinterpret_cast<float4*>(OB + 2*p0)     = make_float4(e0,o0,e1,o1);
        *reinterpret_cast<float4*>(OB + 2*p0 + 4) = make_float4(e2,o2,e3,o3);
    }
    if constexpr (NVEC < NP) {
        int p = NVEC + tid;
        if (p < NP) {
            float e, o;
            synth_pair(XB[p],XB[p+1],XB[p+2],XB[p+3],
                       D[p],D[p+1],D[p+2],D[p+3], e, o);
            OB[2*p]   = e;
            OB[2*p+1] = o;
        }
    }
}

__global__ __launch_bounds__(NT) void idwt_fused_kernel(
    const float* __restrict__ a,
    const float* __restrict__ d6, const float* __restrict__ d5,
    const float* __restrict__ d4, const float* __restrict__ d3,
    const float* __restrict__ d2, const float* __restrict__ d1,
    float* __restrict__ out)
{
    // bufA holds {a-tile(70), L2 out(262), L4 out(1030)}; bufB holds
    // {L1 out(134), L3 out(518), L5 out(2052)}; bufD holds current d-tile.
    __shared__ __align__(16) float bufA[1032], bufB[2056], bufD[2056];

    const int row = blockIdx.y;
    const int K0  = blockIdx.x * T_OUT;
    const int tid = threadIdx.x;

    // ---- L1: stage a + d6 (cols K0>>6, 70 floats each) ----
    {
        const float* ar = a  + (long long)row * 4102 + (K0 >> 6);
        const float* dr = d6 + (long long)row * 4102 + (K0 >> 6);
        if (tid < 70) { bufA[tid] = ar[tid]; bufD[tid] = dr[tid]; }
    }
    __syncthreads();
    level_compute<67, false>(bufA, bufD, bufB, tid);
    __syncthreads();

    // ---- L2: stage d5 (cols K0>>5, 134) ----
    {
        const float* dr = d5 + (long long)row * 8198 + (K0 >> 5);
        if (tid < 134) bufD[tid] = dr[tid];
    }
    __syncthreads();
    level_compute<131, false>(bufB, bufD, bufA, tid);
    __syncthreads();

    // ---- L3: stage d4 (cols K0>>4, 262) ----
    {
        const float* dr = d4 + (long long)row * 16390 + (K0 >> 4);
        for (int i = tid; i < 262; i += NT) bufD[i] = dr[i];
    }
    __syncthreads();
    level_compute<259, false>(bufA, bufD, bufB, tid);
    __syncthreads();

    // ---- L4: stage d3 (cols K0>>3, 518) ----
    {
        const float* dr = d3 + (long long)row * 32774 + (K0 >> 3);
        for (int i = tid; i < 518; i += NT) bufD[i] = dr[i];
    }
    __syncthreads();
    level_compute<515, false>(bufB, bufD, bufA, tid);
    __syncthreads();

    // ---- L5: stage d2 (cols K0>>2, 1029) ----
    {
        const float* dr = d2 + (long long)row * 65541 + (K0 >> 2);
        for (int i = tid; i < 1029; i += NT) bufD[i] = dr[i];
    }
    __syncthreads();
    level_compute<1026, false>(bufA, bufD, bufB, tid);
    __syncthreads();

    // ---- L6: stage d1 (cols K0>>1, 2051), write global ----
    {
        const float* dr = d1 + (long long)row * 131075 + (K0 >> 1);
        for (int i = tid; i < 2051; i += NT) bufD[i] = dr[i];
    }
    __syncthreads();
    float* orow = out + (long long)row * 262144 + K0;   // 2*mlo[6] == K0
    level_compute<2048, true>(bufB, bufD, orow, tid);
}

extern "C" void kernel_launch(void* const* d_in, const int* in_sizes, int n_in,
                              void* d_out, int out_size, void* d_ws, size_t ws_size,
                              hipStream_t stream) {
    const float* a  = (const float*)d_in[0];  // (128, 4102)
    const float* d6 = (const float*)d_in[1];  // (128, 4102)
    const float* d5 = (const float*)d_in[2];  // (128, 8198)
    const float* d4 = (const float*)d_in[3];  // (128, 16390)
    const float* d3 = (const float*)d_in[4];  // (128, 32774)
    const float* d2 = (const float*)d_in[5];  // (128, 65541)
    const float* d1 = (const float*)d_in[6];  // (128, 131075)

    float* OUT = (float*)d_out;               // (128, 262144)

    dim3 block(NT);
    dim3 grid(262144 / T_OUT, 128);           // 64 x 128 = 8192 blocks
    idwt_fused_kernel<<<grid, block, 0, stream>>>(a, d6, d5, d4, d3, d2, d1, OUT);
}

// Round 4
// 51.092 us; speedup vs baseline: 2.6517x; 1.6247x over previous
//
#include <hip/hip_runtime.h>

// 8-tap reconstruction filters (sym4-style), float32.
#define LO0 0.23037781330885523f
#define LO1 0.7148465705525415f
#define LO2 0.6308807679295904f
#define LO3 -0.02798376941698385f
#define LO4 -0.18703481171888114f
#define LO5 0.030841381835986965f
#define LO6 0.032883011666982945f
#define LO7 -0.010597401784997278f

#define HI0 -0.010597401784997278f
#define HI1 -0.032883011666982945f
#define HI2 0.030841381835986965f
#define HI3 0.18703481171888114f
#define HI4 -0.02798376941698385f
#define HI5 -0.6308807679295904f
#define HI6 0.7148465705525415f
#define HI7 -0.23037781330885523f

#define T_OUT 4096
#define NT 256

// Pair counts per level for T_OUT=4096 (identical for every block because
// K0 is a multiple of 4096 -> mlo[l] = K0>>(7-l) exact, X base offset = 0).
// NP: L1=67 L2=131 L3=259 L4=515 L5=1026 L6=2048. Stage counts = NP+3.
// Edge block verified: max read index == len-1 at every level, no clamping.

__device__ __forceinline__ void synth_pair(
    float x0, float x1, float x2, float x3,
    float g0, float g1, float g2, float g3,
    float& e, float& o)
{
    e = x0 * LO6 + g0 * HI6;
    e = fmaf(x1, LO4, e); e = fmaf(g1, HI4, e);
    e = fmaf(x2, LO2, e); e = fmaf(g2, HI2, e);
    e = fmaf(x3, LO0, e); e = fmaf(g3, HI0, e);
    o = x0 * LO7 + g0 * HI7;
    o = fmaf(x1, LO5, o); o = fmaf(g1, HI5, o);
    o = fmaf(x2, LO3, o); o = fmaf(g2, HI3, o);
    o = fmaf(x3, LO1, o); o = fmaf(g3, HI1, o);
}

// One synthesis level: out[2p],out[2p+1] from X[p..p+3], D[p..p+3].
// Vector path: 4 pairs/thread via aligned float4 LDS reads/writes.
template<int NP, bool FINAL>
__device__ __forceinline__ void level_compute(
    const float* __restrict__ XB, const float* __restrict__ D,
    float* __restrict__ OB, int tid)
{
    constexpr int NVEC = NP & ~3;
    for (int p0 = 4 * tid; p0 < NVEC; p0 += 4 * NT) {
        float4 x0 = *reinterpret_cast<const float4*>(XB + p0);
        float4 x1 = *reinterpret_cast<const float4*>(XB + p0 + 4);
        float4 g0 = *reinterpret_cast<const float4*>(D + p0);
        float4 g1 = *reinterpret_cast<const float4*>(D + p0 + 4);
        float e0,o0,e1,o1,e2,o2,e3,o3;
        synth_pair(x0.x,x0.y,x0.z,x0.w, g0.x,g0.y,g0.z,g0.w, e0,o0);
        synth_pair(x0.y,x0.z,x0.w,x1.x, g0.y,g0.z,g0.w,g1.x, e1,o1);
        synth_pair(x0.z,x0.w,x1.x,x1.y, g0.z,g0.w,g1.x,g1.y, e2,o2);
        synth_pair(x0.w,x1.x,x1.y,x1.z, g0.w,g1.x,g1.y,g1.z, e3,o3);
        *reinterpret_cast<float4*>(OB + 2*p0)     = make_float4(e0,o0,e1,o1);
        *reinterpret_cast<float4*>(OB + 2*p0 + 4) = make_float4(e2,o2,e3,o3);
    }
    if constexpr (NVEC < NP) {
        int p = NVEC + tid;
        if (p < NP) {
            float e, o;
            synth_pair(XB[p],XB[p+1],XB[p+2],XB[p+3],
                       D[p],D[p+1],D[p+2],D[p+3], e, o);
            OB[2*p]   = e;
            OB[2*p+1] = o;
        }
    }
}

// Staging helpers: all global loads issued up-front (phase 1), then all LDS
// writes (phase 2) -> single vmcnt drain, no global latency inside the chain.
#define DECL_STAGE(nm, N) \
    constexpr int IT_##nm = ((N) + NT - 1) / NT; \
    float r_##nm[IT_##nm];

#define LOAD_STAGE(nm, N, ptr) \
    _Pragma("unroll") \
    for (int k = 0; k < IT_##nm; ++k) { \
        int i = tid + k * NT; \
        r_##nm[k] = (i < (N)) ? (ptr)[i] : 0.0f; \
    }

#define WRITE_STAGE(nm, N, lds) \
    _Pragma("unroll") \
    for (int k = 0; k < IT_##nm; ++k) { \
        int i = tid + k * NT; \
        if (i < (N)) (lds)[i] = r_##nm[k]; \
    }

__global__ __launch_bounds__(NT) void idwt_fused_kernel(
    const float* __restrict__ a,
    const float* __restrict__ d6, const float* __restrict__ d5,
    const float* __restrict__ d4, const float* __restrict__ d3,
    const float* __restrict__ d2, const float* __restrict__ d1,
    float* __restrict__ out)
{
    // bufA: {a-tile(70), L2 out(262), L4 out(1030)}  (a dead after L1)
    // bufB: {L1 out(134), L3 out(518), L5 out(2052)}
    // D6..D1: per-level detail tiles, all staged in the prologue.
    __shared__ __align__(16) float bufA[1032], bufB[2056];
    __shared__ __align__(16) float D6[72], D5[136], D4[264], D3[520],
                                   D2[1032], D1[2052];

    const int row = blockIdx.y;
    const int K0  = blockIdx.x * T_OUT;
    const int tid = threadIdx.x;

    const float* pa  = a  + (long long)row * 4102   + (K0 >> 6);
    const float* pd6 = d6 + (long long)row * 4102   + (K0 >> 6);
    const float* pd5 = d5 + (long long)row * 8198   + (K0 >> 5);
    const float* pd4 = d4 + (long long)row * 16390  + (K0 >> 4);
    const float* pd3 = d3 + (long long)row * 32774  + (K0 >> 3);
    const float* pd2 = d2 + (long long)row * 65541  + (K0 >> 2);
    const float* pd1 = d1 + (long long)row * 131075 + (K0 >> 1);

    DECL_STAGE(a, 70)    DECL_STAGE(D6, 70)   DECL_STAGE(D5, 134)
    DECL_STAGE(D4, 262)  DECL_STAGE(D3, 518)  DECL_STAGE(D2, 1029)
    DECL_STAGE(D1, 2051)

    // Phase 1: issue ALL global loads (stay in flight together).
    LOAD_STAGE(a,  70,   pa)
    LOAD_STAGE(D6, 70,   pd6)
    LOAD_STAGE(D5, 134,  pd5)
    LOAD_STAGE(D4, 262,  pd4)
    LOAD_STAGE(D3, 518,  pd3)
    LOAD_STAGE(D2, 1029, pd2)
    LOAD_STAGE(D1, 2051, pd1)

    // Phase 2: drain into LDS.
    WRITE_STAGE(a,  70,   bufA)
    WRITE_STAGE(D6, 70,   D6)
    WRITE_STAGE(D5, 134,  D5)
    WRITE_STAGE(D4, 262,  D4)
    WRITE_STAGE(D3, 518,  D3)
    WRITE_STAGE(D2, 1029, D2)
    WRITE_STAGE(D1, 2051, D1)

    __syncthreads();

    // Pure LDS+VALU level chain: 5 inter-level barriers, no global waits.
    level_compute<67,   false>(bufA, D6, bufB, tid);
    __syncthreads();
    level_compute<131,  false>(bufB, D5, bufA, tid);
    __syncthreads();
    level_compute<259,  false>(bufA, D4, bufB, tid);
    __syncthreads();
    level_compute<515,  false>(bufB, D3, bufA, tid);
    __syncthreads();
    level_compute<1026, false>(bufA, D2, bufB, tid);
    __syncthreads();

    float* orow = out + (long long)row * 262144 + K0;   // 2*mlo[6] == K0
    level_compute<2048, true>(bufB, D1, orow, tid);
}

extern "C" void kernel_launch(void* const* d_in, const int* in_sizes, int n_in,
                              void* d_out, int out_size, void* d_ws, size_t ws_size,
                              hipStream_t stream) {
    const float* a  = (const float*)d_in[0];  // (128, 4102)
    const float* d6 = (const float*)d_in[1];  // (128, 4102)
    const float* d5 = (const float*)d_in[2];  // (128, 8198)
    const float* d4 = (const float*)d_in[3];  // (128, 16390)
    const float* d3 = (const float*)d_in[4];  // (128, 32774)
    const float* d2 = (const float*)d_in[5];  // (128, 65541)
    const float* d1 = (const float*)d_in[6];  // (128, 131075)

    float* OUT = (float*)d_out;               // (128, 262144)

    dim3 block(NT);
    dim3 grid(262144 / T_OUT, 128);           // 64 x 128 = 8192 blocks
    idwt_fused_kernel<<<grid, block, 0, stream>>>(a, d6, d5, d4, d3, d2, d1, OUT);
}

// Round 5
// 49.972 us; speedup vs baseline: 2.7111x; 1.0224x over previous
//
#include <hip/hip_runtime.h>

// 8-tap reconstruction filters (sym4-style), float32.
#define LO0 0.23037781330885523f
#define LO1 0.7148465705525415f
#define LO2 0.6308807679295904f
#define LO3 -0.02798376941698385f
#define LO4 -0.18703481171888114f
#define LO5 0.030841381835986965f
#define LO6 0.032883011666982945f
#define LO7 -0.010597401784997278f

#define HI0 -0.010597401784997278f
#define HI1 -0.032883011666982945f
#define HI2 0.030841381835986965f
#define HI3 0.18703481171888114f
#define HI4 -0.02798376941698385f
#define HI5 -0.6308807679295904f
#define HI6 0.7148465705525415f
#define HI7 -0.23037781330885523f

#define T_OUT 4096
#define NT 256

// Pair counts per level for T_OUT=4096 (identical for every block because
// K0 is a multiple of 4096 -> mlo[l] = K0>>(7-l) exact, X base offset = 0).
// NP: L1=67 L2=131 L3=259 L4=515 L5=1026 L6=2048. Stage counts = NP+3.
// Edge block verified: max read index == len-1 at every level, no clamping.

__device__ __forceinline__ void synth_pair(
    float x0, float x1, float x2, float x3,
    float g0, float g1, float g2, float g3,
    float& e, float& o)
{
    e = x0 * LO6 + g0 * HI6;
    e = fmaf(x1, LO4, e); e = fmaf(g1, HI4, e);
    e = fmaf(x2, LO2, e); e = fmaf(g2, HI2, e);
    e = fmaf(x3, LO0, e); e = fmaf(g3, HI0, e);
    o = x0 * LO7 + g0 * HI7;
    o = fmaf(x1, LO5, o); o = fmaf(g1, HI5, o);
    o = fmaf(x2, LO3, o); o = fmaf(g2, HI3, o);
    o = fmaf(x3, LO1, o); o = fmaf(g3, HI1, o);
}

// One synthesis level: out[2p],out[2p+1] from X[p..p+3], D[p..p+3].
// Vector path: 4 pairs/thread via aligned float4 LDS reads/writes.
template<int NP>
__device__ __forceinline__ void level_compute(
    const float* __restrict__ XB, const float* __restrict__ D,
    float* __restrict__ OB, int tid)
{
    constexpr int NVEC = NP & ~3;
    for (int p0 = 4 * tid; p0 < NVEC; p0 += 4 * NT) {
        float4 x0 = *reinterpret_cast<const float4*>(XB + p0);
        float4 x1 = *reinterpret_cast<const float4*>(XB + p0 + 4);
        float4 g0 = *reinterpret_cast<const float4*>(D + p0);
        float4 g1 = *reinterpret_cast<const float4*>(D + p0 + 4);
        float e0,o0,e1,o1,e2,o2,e3,o3;
        synth_pair(x0.x,x0.y,x0.z,x0.w, g0.x,g0.y,g0.z,g0.w, e0,o0);
        synth_pair(x0.y,x0.z,x0.w,x1.x, g0.y,g0.z,g0.w,g1.x, e1,o1);
        synth_pair(x0.z,x0.w,x1.x,x1.y, g0.z,g0.w,g1.x,g1.y, e2,o2);
        synth_pair(x0.w,x1.x,x1.y,x1.z, g0.w,g1.x,g1.y,g1.z, e3,o3);
        *reinterpret_cast<float4*>(OB + 2*p0)     = make_float4(e0,o0,e1,o1);
        *reinterpret_cast<float4*>(OB + 2*p0 + 4) = make_float4(e2,o2,e3,o3);
    }
    if constexpr (NVEC < NP) {
        int p = NVEC + tid;
        if (p < NP) {
            float e, o;
            synth_pair(XB[p],XB[p+1],XB[p+2],XB[p+3],
                       D[p],D[p+1],D[p+2],D[p+3], e, o);
            OB[2*p]   = e;
            OB[2*p+1] = o;
        }
    }
}

// 4-pair group with register-resident g values (indices compile-time after
// unroll). Used for the final level (D1 never staged to LDS).
__device__ __forceinline__ void synth_group4_reg(
    const float* __restrict__ XB, int p0, const float* g, float* __restrict__ OB)
{
    float4 x0 = *reinterpret_cast<const float4*>(XB + p0);
    float4 x1 = *reinterpret_cast<const float4*>(XB + p0 + 4);
    float e0,o0,e1,o1,e2,o2,e3,o3;
    synth_pair(x0.x,x0.y,x0.z,x0.w, g[0],g[1],g[2],g[3], e0,o0);
    synth_pair(x0.y,x0.z,x0.w,x1.x, g[1],g[2],g[3],g[4], e1,o1);
    synth_pair(x0.z,x0.w,x1.x,x1.y, g[2],g[3],g[4],g[5], e2,o2);
    synth_pair(x0.w,x1.x,x1.y,x1.z, g[3],g[4],g[5],g[6], e3,o3);
    *reinterpret_cast<float4*>(OB + 2*p0)     = make_float4(e0,o0,e1,o1);
    *reinterpret_cast<float4*>(OB + 2*p0 + 4) = make_float4(e2,o2,e3,o3);
}

// Async global->LDS DMA staging (linear dest == wave-uniform base + lane*4).
// Tail waves/lanes are exec-masked off; first active lane is always the
// lowest lane of each wave, so the readfirstlane'd LDS base stays correct.
typedef const __attribute__((address_space(1))) unsigned int* as1_u32_cptr;
typedef __attribute__((address_space(3))) unsigned int* as3_u32_ptr;

__device__ __forceinline__ void stage_async(const float* __restrict__ g,
                                            float* __restrict__ l,
                                            int n, int tid)
{
    for (int i = tid; i < n; i += NT) {
        __builtin_amdgcn_global_load_lds((as1_u32_cptr)(g + i),
                                         (as3_u32_ptr)(l + i), 4, 0, 0);
    }
}

__global__ __launch_bounds__(NT) void idwt_fused_kernel(
    const float* __restrict__ a,
    const float* __restrict__ d6, const float* __restrict__ d5,
    const float* __restrict__ d4, const float* __restrict__ d3,
    const float* __restrict__ d2, const float* __restrict__ d1,
    float* __restrict__ out)
{
    // bufA: {a-tile(70), L2 out(262), L4 out(1030)}
    // bufB: {L1 out(134), L3 out(518), L5 out(2052)}
    // D6..D2 staged by DMA; D1 lives in registers only.
    // Total LDS = (1032+2056+72+136+264+520+1032)*4 = 20448 B -> 8 blocks/CU.
    __shared__ __align__(16) float bufA[1032], bufB[2056];
    __shared__ __align__(16) float D6[72], D5[136], D4[264], D3[520], D2[1032];

    const int row = blockIdx.y;
    const int K0  = blockIdx.x * T_OUT;
    const int tid = threadIdx.x;

    const float* pa  = a  + (long long)row * 4102   + (K0 >> 6);
    const float* pd6 = d6 + (long long)row * 4102   + (K0 >> 6);
    const float* pd5 = d5 + (long long)row * 8198   + (K0 >> 5);
    const float* pd4 = d4 + (long long)row * 16390  + (K0 >> 4);
    const float* pd3 = d3 + (long long)row * 32774  + (K0 >> 3);
    const float* pd2 = d2 + (long long)row * 65541  + (K0 >> 2);
    const float* pd1 = d1 + (long long)row * 131075 + (K0 >> 1);

    // Phase 1: DMA-stage all LDS-destined tiles (async, no VGPR data path).
    stage_async(pa,  bufA, 70,   tid);
    stage_async(pd6, D6,   70,   tid);
    stage_async(pd5, D5,   134,  tid);
    stage_async(pd4, D4,   262,  tid);
    stage_async(pd3, D3,   518,  tid);
    stage_async(pd2, D2,   1029, tid);

    // Phase 2: D1 straight to registers. Group A needs D1[4t..4t+6],
    // group B needs D1[4t+1024..4t+1030]; max index 2050 == tile end. The
    // ~2x within-wave address overlap hits L1 (same lines, same moment).
    float d1A[7], d1B[7];
#pragma unroll
    for (int j = 0; j < 7; ++j) d1A[j] = pd1[4 * tid + j];
#pragma unroll
    for (int j = 0; j < 7; ++j) d1B[j] = pd1[4 * tid + 1024 + j];

    __syncthreads();   // drains vmcnt(0): DMA + d1 regs all resident

    // Pure LDS+VALU level chain: 5 inter-level barriers, no global waits.
    level_compute<67>  (bufA, D6, bufB, tid);
    __syncthreads();
    level_compute<131> (bufB, D5, bufA, tid);
    __syncthreads();
    level_compute<259> (bufA, D4, bufB, tid);
    __syncthreads();
    level_compute<515> (bufB, D3, bufA, tid);
    __syncthreads();
    level_compute<1026>(bufA, D2, bufB, tid);
    __syncthreads();

    // L6: 2048 pairs, two 4-pair groups per thread, g from registers,
    // output straight to global (16B-aligned: rows are 1 MiB apart).
    float* orow = out + (long long)row * 262144 + K0;   // 2*mlo[6] == K0
    synth_group4_reg(bufB, 4 * tid,        d1A, orow);
    synth_group4_reg(bufB, 4 * tid + 1024, d1B, orow);
}

extern "C" void kernel_launch(void* const* d_in, const int* in_sizes, int n_in,
                              void* d_out, int out_size, void* d_ws, size_t ws_size,
                              hipStream_t stream) {
    const float* a  = (const float*)d_in[0];  // (128, 4102)
    const float* d6 = (const float*)d_in[1];  // (128, 4102)
    const float* d5 = (const float*)d_in[2];  // (128, 8198)
    const float* d4 = (const float*)d_in[3];  // (128, 16390)
    const float* d3 = (const float*)d_in[4];  // (128, 32774)
    const float* d2 = (const float*)d_in[5];  // (128, 65541)
    const float* d1 = (const float*)d_in[6];  // (128, 131075)

    float* OUT = (float*)d_out;               // (128, 262144)

    dim3 block(NT);
    dim3 grid(262144 / T_OUT, 128);           // 64 x 128 = 8192 blocks
    idwt_fused_kernel<<<grid, block, 0, stream>>>(a, d6, d5, d4, d3, d2, d1, OUT);
}

// Round 6
// 48.757 us; speedup vs baseline: 2.7786x; 1.0249x over previous
//
#include <hip/hip_runtime.h>

// 8-tap reconstruction filters (sym4-style), float32.
#define LO0 0.23037781330885523f
#define LO1 0.7148465705525415f
#define LO2 0.6308807679295904f
#define LO3 -0.02798376941698385f
#define LO4 -0.18703481171888114f
#define LO5 0.030841381835986965f
#define LO6 0.032883011666982945f
#define LO7 -0.010597401784997278f

#define HI0 -0.010597401784997278f
#define HI1 -0.032883011666982945f
#define HI2 0.030841381835986965f
#define HI3 0.18703481171888114f
#define HI4 -0.02798376941698385f
#define HI5 -0.6308807679295904f
#define HI6 0.7148465705525415f
#define HI7 -0.23037781330885523f

#define NT 256   // 4 waves; each wave owns an independent 1024-col output tile

// Per-wave pair counts (T=1024, K0w multiple of 1024 -> all ranges exact,
// base offset 0 at every level):
//   L1=19 L2=35 L3=67 L4=131 L5=258 L6=512; staged inputs = NP+3.
// Edge wave verified: max read index == len-1 at every level, no clamping.

__device__ __forceinline__ void synth_pair(
    float x0, float x1, float x2, float x3,
    float g0, float g1, float g2, float g3,
    float& e, float& o)
{
    e = x0 * LO6 + g0 * HI6;
    e = fmaf(x1, LO4, e); e = fmaf(g1, HI4, e);
    e = fmaf(x2, LO2, e); e = fmaf(g2, HI2, e);
    e = fmaf(x3, LO0, e); e = fmaf(g3, HI0, e);
    o = x0 * LO7 + g0 * HI7;
    o = fmaf(x1, LO5, o); o = fmaf(g1, HI5, o);
    o = fmaf(x2, LO3, o); o = fmaf(g2, HI3, o);
    o = fmaf(x3, LO1, o); o = fmaf(g3, HI1, o);
}

// 4 pairs from LDS X + LDS D, write 8 outputs (2x float4).
__device__ __forceinline__ void synth_group4_lds(
    const float* __restrict__ XB, const float* __restrict__ D,
    float* __restrict__ OB, int p0)
{
    float4 x0 = *reinterpret_cast<const float4*>(XB + p0);
    float4 x1 = *reinterpret_cast<const float4*>(XB + p0 + 4);
    float4 g0 = *reinterpret_cast<const float4*>(D + p0);
    float4 g1 = *reinterpret_cast<const float4*>(D + p0 + 4);
    float e0,o0,e1,o1,e2,o2,e3,o3;
    synth_pair(x0.x,x0.y,x0.z,x0.w, g0.x,g0.y,g0.z,g0.w, e0,o0);
    synth_pair(x0.y,x0.z,x0.w,x1.x, g0.y,g0.z,g0.w,g1.x, e1,o1);
    synth_pair(x0.z,x0.w,x1.x,x1.y, g0.z,g0.w,g1.x,g1.y, e2,o2);
    synth_pair(x0.w,x1.x,x1.y,x1.z, g0.w,g1.x,g1.y,g1.z, e3,o3);
    *reinterpret_cast<float4*>(OB + 2*p0)     = make_float4(e0,o0,e1,o1);
    *reinterpret_cast<float4*>(OB + 2*p0 + 4) = make_float4(e2,o2,e3,o3);
}

// 4 pairs with register-resident g[0..6] (D2/D1 paths).
__device__ __forceinline__ void synth_group4_reg(
    const float* __restrict__ XB, int p0, const float* g, float* __restrict__ OB)
{
    float4 x0 = *reinterpret_cast<const float4*>(XB + p0);
    float4 x1 = *reinterpret_cast<const float4*>(XB + p0 + 4);
    float e0,o0,e1,o1,e2,o2,e3,o3;
    synth_pair(x0.x,x0.y,x0.z,x0.w, g[0],g[1],g[2],g[3], e0,o0);
    synth_pair(x0.y,x0.z,x0.w,x1.x, g[1],g[2],g[3],g[4], e1,o1);
    synth_pair(x0.z,x0.w,x1.x,x1.y, g[2],g[3],g[4],g[5], e2,o2);
    synth_pair(x0.w,x1.x,x1.y,x1.z, g[3],g[4],g[5],g[6], e3,o3);
    *reinterpret_cast<float4*>(OB + 2*p0)     = make_float4(e0,o0,e1,o1);
    *reinterpret_cast<float4*>(OB + 2*p0 + 4) = make_float4(e2,o2,e3,o3);
}

// Generic per-wave level: NVEC <= 256 -> one predicated vec group per lane
// plus a <=3-pair scalar tail.
template<int NP>
__device__ __forceinline__ void wave_level(
    const float* __restrict__ XB, const float* __restrict__ D,
    float* __restrict__ OB, int lane)
{
    constexpr int NVEC = NP & ~3;
    static_assert(NVEC <= 256, "one vec group per lane");
    if (4 * lane < NVEC) synth_group4_lds(XB, D, OB, 4 * lane);
    if constexpr (NVEC < NP) {
        int p = NVEC + lane;
        if (p < NP) {
            float e, o;
            synth_pair(XB[p],XB[p+1],XB[p+2],XB[p+3],
                       D[p],D[p+1],D[p+2],D[p+3], e, o);
            OB[2*p]   = e;
            OB[2*p+1] = o;
        }
    }
}

// Async global->LDS DMA (linear dest == wave-uniform base + lane*4).
typedef const __attribute__((address_space(1))) unsigned int* as1_u32_cptr;
typedef __attribute__((address_space(3))) unsigned int* as3_u32_ptr;

__device__ __forceinline__ void stage_async_w(const float* __restrict__ g,
                                              float* __restrict__ l,
                                              int n, int lane)
{
    for (int i = lane; i < n; i += 64) {
        __builtin_amdgcn_global_load_lds((as1_u32_cptr)(g + i),
                                         (as3_u32_ptr)(l + i), 4, 0, 0);
    }
}

__global__ __launch_bounds__(NT) void idwt_fused_kernel(
    const float* __restrict__ a,
    const float* __restrict__ d6, const float* __restrict__ d5,
    const float* __restrict__ d4, const float* __restrict__ d3,
    const float* __restrict__ d2, const float* __restrict__ d1,
    float* __restrict__ out)
{
    // Per-wave regions; no cross-wave sharing -> ZERO barriers.
    // sA[w]: a-tile(22) -> L2 out(70) -> L4 out(262)
    // sB[w]: L1 out(38) -> L3 out(134) -> L5 out(516)
    // D2 and D1 live in registers only.
    // Total LDS = 4*(264+520+24+40+72+136)*4 = 16896 B -> 8 blocks/CU.
    __shared__ __align__(16) float sA[4][264];
    __shared__ __align__(16) float sB[4][520];
    __shared__ __align__(16) float sD6[4][24];
    __shared__ __align__(16) float sD5[4][40];
    __shared__ __align__(16) float sD4[4][72];
    __shared__ __align__(16) float sD3[4][136];

    const int row  = blockIdx.y;
    const int wid  = threadIdx.x >> 6;
    const int lane = threadIdx.x & 63;
    const int K0w  = blockIdx.x * 4096 + wid * 1024;

    const float* pa  = a  + (long long)row * 4102   + (K0w >> 6);
    const float* pd6 = d6 + (long long)row * 4102   + (K0w >> 6);
    const float* pd5 = d5 + (long long)row * 8198   + (K0w >> 5);
    const float* pd4 = d4 + (long long)row * 16390  + (K0w >> 4);
    const float* pd3 = d3 + (long long)row * 32774  + (K0w >> 3);
    const float* pd2 = d2 + (long long)row * 65541  + (K0w >> 2);
    const float* pd1 = d1 + (long long)row * 131075 + (K0w >> 1);

    // Issue all DMA staging (async), plus D2 register loads, then one drain.
    stage_async_w(pa,  sA[wid],  22,  lane);
    stage_async_w(pd6, sD6[wid], 22,  lane);
    stage_async_w(pd5, sD5[wid], 38,  lane);
    stage_async_w(pd4, sD4[wid], 70,  lane);
    stage_async_w(pd3, sD3[wid], 134, lane);

    float d2r[7];
#pragma unroll
    for (int j = 0; j < 7; ++j) d2r[j] = pd2[4 * lane + j];
    float d2t[4];
    if (lane < 2) {
#pragma unroll
        for (int j = 0; j < 4; ++j) d2t[j] = pd2[256 + lane + j];
    }

    asm volatile("s_waitcnt vmcnt(0)" ::: "memory");

    // ---- L1 (19 pairs, scalar, lanes 0..18) ----
    if (lane < 19) {
        float e, o;
        synth_pair(sA[wid][lane], sA[wid][lane+1], sA[wid][lane+2], sA[wid][lane+3],
                   sD6[wid][lane], sD6[wid][lane+1], sD6[wid][lane+2], sD6[wid][lane+3],
                   e, o);
        sB[wid][2*lane]   = e;
        sB[wid][2*lane+1] = o;
    }

    // D1 register loads issued here: latency hides under L2..L5.
    float d1A[7], d1B[7];
#pragma unroll
    for (int j = 0; j < 7; ++j) d1A[j] = pd1[4 * lane + j];
#pragma unroll
    for (int j = 0; j < 7; ++j) d1B[j] = pd1[4 * lane + 256 + j];

    // ---- L2..L4: pure per-wave LDS chain, lgkmcnt-ordered, no barriers ----
    wave_level<35> (sB[wid], sD5[wid], sA[wid], lane);
    wave_level<67> (sA[wid], sD4[wid], sB[wid], lane);
    wave_level<131>(sB[wid], sD3[wid], sA[wid], lane);

    // ---- L5 (258 pairs): vec from D2 regs + 2-pair tail ----
    synth_group4_reg(sA[wid], 4 * lane, d2r, sB[wid]);
    if (lane < 2) {
        int p = 256 + lane;
        float e, o;
        synth_pair(sA[wid][p], sA[wid][p+1], sA[wid][p+2], sA[wid][p+3],
                   d2t[0], d2t[1], d2t[2], d2t[3], e, o);
        sB[wid][2*p]   = e;
        sB[wid][2*p+1] = o;
    }

    // ---- L6 (512 pairs): two vec groups from D1 regs, straight to global ----
    float* orow = out + (long long)row * 262144 + K0w;
    synth_group4_reg(sB[wid], 4 * lane,       d1A, orow);
    synth_group4_reg(sB[wid], 4 * lane + 256, d1B, orow);
}

extern "C" void kernel_launch(void* const* d_in, const int* in_sizes, int n_in,
                              void* d_out, int out_size, void* d_ws, size_t ws_size,
                              hipStream_t stream) {
    const float* a  = (const float*)d_in[0];  // (128, 4102)
    const float* d6 = (const float*)d_in[1];  // (128, 4102)
    const float* d5 = (const float*)d_in[2];  // (128, 8198)
    const float* d4 = (const float*)d_in[3];  // (128, 16390)
    const float* d3 = (const float*)d_in[4];  // (128, 32774)
    const float* d2 = (const float*)d_in[5];  // (128, 65541)
    const float* d1 = (const float*)d_in[6];  // (128, 131075)

    float* OUT = (float*)d_out;               // (128, 262144)

    dim3 block(NT);
    dim3 grid(64, 128);                       // 64 x 128 = 8192 blocks, 4 waves each
    idwt_fused_kernel<<<grid, block, 0, stream>>>(a, d6, d5, d4, d3, d2, d1, OUT);
}